// Round 3
// baseline (154.918 us; speedup 1.0000x reference)
//
#include <hip/hip_runtime.h>

// Problem constants
//   m1:(1,1,4096,64) m2:(1,1,6144,64) m3:(1,1,8192,64) m4:(1,1,4096,64) fp32
//   WQ_w:(3,64,64) WQ_b:(3,64) WK_w:(4,3,64,64) WK_b:(4,3,64)
//   out:(1,4096,32) fp32
//
// Workspace layout (floats):
//   Q    row-major [4096][64]            @ 0          (262144)
//   K_T  per module [64][T_m]            @ 262144     (1441792)
//   SP   356 slots x 2048 (d*32+e)       @ 1703936    (729088)
//   TD   dense t2 per module             @ 2433024    (22528)

#define QT_OFF   0
#define KT_OFF   262144
#define SP_OFF   1703936
#define TD_OFF   2433024

// ---------------------------------------------------------------------------
// Fused MLP + per-tile chunk outer-product sums.
// 128-row tiles, 2 rows/thread, W staged one layer at a time.
// Tiles: Q:32 | K m0:32 | m1:48 | m2:64 | m3:32  -> 208 blocks.
// K-task blocks additionally compute their 2 chunk sums (K V^T over 64 rows)
// straight from LDS-resident K and write them to SP slots (k_chunks fused).
__global__ __launch_bounds__(256) void k_fused(
    const float* __restrict__ x0, const float* __restrict__ x1,
    const float* __restrict__ x2, const float* __restrict__ x3,
    const float* __restrict__ wq_w, const float* __restrict__ wq_b,
    const float* __restrict__ wk_w, const float* __restrict__ wk_b,
    float* __restrict__ ws)
{
    __shared__ float sW[64*64];    // 16 KB: W layer; reused as V tile [128][32]
    __shared__ float sH[64*130];   // 33.3 KB: h[d][r]; reused as K[d][r]
    __shared__ float so[64*33];    // 8.4 KB: chunk-output transpose staging

    const int tid = threadIdx.x;
    const int bid = blockIdx.x;

    int task, rb;
    if (bid < 32)       { task = 0; rb = bid; }
    else if (bid < 64)  { task = 1; rb = bid - 32; }
    else if (bid < 112) { task = 2; rb = bid - 64; }
    else if (bid < 176) { task = 3; rb = bid - 112; }
    else                { task = 4; rb = bid - 176; }

    const float* Xs[4] = {x0, x1, x2, x3};
    const int Tm[4]     = {4096, 6144, 8192, 4096};
    const int rowoff[4] = {0, 4096, 10240, 18432};
    const int spoff[4]  = {0, 65, 162, 291};

    const float* X; const float* W; const float* Bv;
    int mm = -1;
    if (task == 0) { X = x0; W = wq_w; Bv = wq_b; }
    else {
        mm = task - 1;
        X = Xs[mm]; W = wk_w + mm*3*64*64; Bv = wk_b + mm*3*64;
    }

    const int row0 = rb * 128;
    const float4* X4 = (const float4*)(X + (size_t)row0*64);
    #pragma unroll
    for (int k = 0; k < 8; ++k) {
        int idx = k*256 + tid;            // float4 index in 128x64 tile
        float4 v = X4[idx];
        int db = idx * 4;
        int d0 = db & 63;
        int rr = db >> 6;                 // 0..127
        sH[(d0+0)*130 + rr] = v.x;
        sH[(d0+1)*130 + rr] = v.y;
        sH[(d0+2)*130 + rr] = v.z;
        sH[(d0+3)*130 + rr] = v.w;
    }
    __syncthreads();
    // dense t extraction (K tasks cover all modules)
    if (task > 0 && tid < 128)
        ws[TD_OFF + rowoff[mm] + row0 + tid] = sH[63*130 + tid];

    const int r  = tid & 63;
    const int cb = (tid >> 6) * 16;

    float a0[16], a1[16];
    #pragma unroll 1
    for (int l = 0; l < 3; ++l) {
        __syncthreads();                  // prev reads of sW/sH done
        const float4* W4 = (const float4*)(W + l*4096);
        #pragma unroll
        for (int k = 0; k < 4; ++k)
            ((float4*)sW)[k*256 + tid] = W4[k*256 + tid];
        __syncthreads();

        #pragma unroll
        for (int c = 0; c < 16; ++c) {
            float b = Bv[l*64 + cb + c];
            a0[c] = b; a1[c] = b;
        }
        for (int d = 0; d < 64; ++d) {
            float h0 = sH[d*130 + r];
            float h1 = sH[d*130 + 64 + r];
            #pragma unroll
            for (int c = 0; c < 16; ++c) {
                float w = sW[d*64 + cb + c];   // wave-uniform broadcast
                a0[c] += h0 * w;
                a1[c] += h1 * w;
            }
        }
        if (l < 2) {
            #pragma unroll
            for (int c = 0; c < 16; ++c) {
                a0[c] = fmaxf(a0[c], 0.0f);
                a1[c] = fmaxf(a1[c], 0.0f);
            }
            __syncthreads();
            #pragma unroll
            for (int c = 0; c < 16; ++c) {
                sH[(cb+c)*130 + r]      = a0[c];
                sH[(cb+c)*130 + 64 + r] = a1[c];
            }
        }
    }

    if (task == 0) {
        // Q row-major store: rows r, r+64; 16 consecutive cols at cb
        float* q0 = ws + QT_OFF + (size_t)(row0 + r)*64 + cb;
        float* q1 = ws + QT_OFF + (size_t)(row0 + 64 + r)*64 + cb;
        #pragma unroll
        for (int k = 0; k < 4; ++k) {
            ((float4*)q0)[k] = make_float4(a0[4*k], a0[4*k+1], a0[4*k+2], a0[4*k+3]);
            ((float4*)q1)[k] = make_float4(a1[4*k], a1[4*k+1], a1[4*k+2], a1[4*k+3]);
        }
        return;
    }

    // K task: store K_T global (for k_query remainders)
    {
        float* outT = ws + KT_OFF + (size_t)64*rowoff[mm];
        const int stride = Tm[mm];
        #pragma unroll
        for (int c = 0; c < 16; ++c) {
            outT[(size_t)(cb+c)*stride + row0 + r]      = a0[c];
            outT[(size_t)(cb+c)*stride + row0 + 64 + r] = a1[c];
        }
    }
    __syncthreads();                      // everyone done reading sH (layer-2 acts)
    // write K into sH[d][r]
    #pragma unroll
    for (int c = 0; c < 16; ++c) {
        sH[(cb+c)*130 + r]      = a0[c];
        sH[(cb+c)*130 + 64 + r] = a1[c];
    }
    // reload V tile (first 32 cols of X rows) into sW
    {
        const float4* Xr = (const float4*)(X + (size_t)row0*64);
        #pragma unroll
        for (int k = 0; k < 4; ++k) {
            int idx = k*256 + tid;        // 0..1023
            int rr = idx >> 3, c4 = idx & 7;
            ((float4*)sW)[rr*8 + c4] = Xr[rr*16 + c4];
        }
    }
    float* spbase = ws + SP_OFF + (size_t)spoff[mm]*2048;
    if (rb == 0)                          // zero the module's slot 0
        for (int idx = tid; idx < 2048; idx += 256) spbase[idx] = 0.0f;
    __syncthreads();

    // chunk sums: thread (d = tid&63, eg = tid>>6 wave-uniform)
    const int d  = tid & 63;
    const int eg = tid >> 6;
    const float4* vb4 = (const float4*)sW;
    #pragma unroll 1
    for (int pass = 0; pass < 2; ++pass) {
        float acc[8] = {0,0,0,0,0,0,0,0};
        for (int j = 0; j < 64; ++j) {
            int rr = pass*64 + j;
            float  kd = sH[d*130 + rr];          // 2-way alias only -> free
            float4 vA = vb4[rr*8 + eg*2 + 0];    // broadcast b128
            float4 vB = vb4[rr*8 + eg*2 + 1];
            acc[0] += kd * vA.x; acc[1] += kd * vA.y;
            acc[2] += kd * vA.z; acc[3] += kd * vA.w;
            acc[4] += kd * vB.x; acc[5] += kd * vB.y;
            acc[6] += kd * vB.z; acc[7] += kd * vB.w;
        }
        #pragma unroll
        for (int u = 0; u < 8; ++u)
            so[d*33 + eg*8 + u] = acc[u];
        __syncthreads();
        float* slot = spbase + (size_t)(2*rb + pass + 1) * 2048;
        for (int idx = tid; idx < 2048; idx += 256)
            slot[idx] = so[(idx >> 5)*33 + (idx & 31)];
        __syncthreads();
    }
}

// ---------------------------------------------------------------------------
// In-place scan over slots. 128 blocks x 64 threads (one thread per chain).
__global__ __launch_bounds__(64) void k_prefix(float* __restrict__ ws)
{
    const int nslots[4] = {65, 97, 129, 65};
    const int spoff[4]  = {0, 65, 162, 291};
    const int m = blockIdx.x >> 5;
    const int entry = (blockIdx.x & 31)*64 + threadIdx.x;
    float* p = ws + SP_OFF + (size_t)spoff[m]*2048 + entry;
    const int n = nslots[m];
    float s = 0.0f;
    #pragma unroll 8
    for (int k = 0; k < n; ++k) {
        float v = p[(size_t)k*2048];
        s += v;
        p[(size_t)k*2048] = s;
    }
}

// ---------------------------------------------------------------------------
// Block per query PAIR (2048 blocks); wave m handles module m for both.
// XCD-swizzled: each XCD gets a contiguous time range. Adjacent queries share
// slot/chunk -> second query's loads hit L1.
__global__ __launch_bounds__(256) void k_query(
    const float* __restrict__ x0, const float* __restrict__ x1,
    const float* __restrict__ x2, const float* __restrict__ x3,
    const float* __restrict__ ws, float* __restrict__ out)
{
    __shared__ float red[2][4][32];
    const int tid  = threadIdx.x;
    const int bid  = blockIdx.x;
    const int ib   = ((bid & 7) << 8) | (bid >> 3);   // XCD swizzle over 2048
    const int i0   = 2*ib, i1 = i0 + 1;
    const int m    = tid >> 6;
    const int lane = tid & 63;
    const int e    = lane & 31;
    const int h    = lane >> 5;

    const float* Xs[4] = {x0, x1, x2, x3};
    const int Tm[4]     = {4096, 6144, 8192, 4096};
    const int rowoff[4] = {0, 4096, 10240, 18432};
    const int spoff[4]  = {0, 65, 162, 291};

    const float* X = Xs[m];
    const int T = Tm[m];
    const float* td = ws + TD_OFF;
    const float* t2 = td + rowoff[m];
    const float ta = td[i0];
    const float tb = td[i1];

    // c0 by binary search; c1 by linear extension (t sorted, small gap)
    int lo = 0, hi = T;
    while (lo < hi) {
        int mid = (lo + hi) >> 1;
        if (t2[mid] <= ta) lo = mid + 1; else hi = mid;
    }
    const int c0 = lo;
    int c1 = c0;
    while (c1 < T && t2[c1] <= tb) ++c1;

    const int b0 = c0 >> 6, rem0 = c0 & 63;
    const int b1 = c1 >> 6, rem1 = c1 & 63;

    const float* qr0 = ws + QT_OFF + (size_t)i0*64;
    const float* qr1 = ws + QT_OFF + (size_t)i1*64;
    const float* Kt  = ws + KT_OFF + (size_t)64*rowoff[m];
    const float* sp0 = ws + SP_OFF + (size_t)(spoff[m] + b0)*2048;
    const float* sp1 = ws + SP_OFF + (size_t)(spoff[m] + b1)*2048;

    float acc0 = 0.0f, acc1 = 0.0f;
    // state part: half-wave h covers d in [h*32, h*32+32)
    #pragma unroll 8
    for (int dd = 0; dd < 32; ++dd) {
        int d = h*32 + dd;
        float s0 = sp0[d*32 + e];
        float s1 = sp1[d*32 + e];      // usually same line -> L1 hit
        acc0 += qr0[d] * s0;
        acc1 += qr1[d] * s1;
    }
    // remainder for query 0
    if (rem0 > 0) {
        const int jb = b0 * 64;
        float s = 0.0f;
        if (lane < rem0) {
            #pragma unroll 8
            for (int d = 0; d < 64; ++d)
                s += qr0[d] * Kt[(size_t)d*T + jb + lane];
        }
        const int nu = (rem0 + 1) >> 1;
        #pragma unroll 4
        for (int u = 0; u < nu; ++u) {
            int lh = 2*u + h;
            float sl = __shfl(s, lh, 64);
            if (lh < rem0) acc0 += sl * X[(size_t)(jb + lh)*64 + e];
        }
    }
    // remainder for query 1 (same chunk most of the time -> L1 hits)
    if (rem1 > 0) {
        const int jb = b1 * 64;
        float s = 0.0f;
        if (lane < rem1) {
            #pragma unroll 8
            for (int d = 0; d < 64; ++d)
                s += qr1[d] * Kt[(size_t)d*T + jb + lane];
        }
        const int nu = (rem1 + 1) >> 1;
        #pragma unroll 4
        for (int u = 0; u < nu; ++u) {
            int lh = 2*u + h;
            float sl = __shfl(s, lh, 64);
            if (lh < rem1) acc1 += sl * X[(size_t)(jb + lh)*64 + e];
        }
    }

    acc0 += __shfl_xor(acc0, 32, 64);
    acc1 += __shfl_xor(acc1, 32, 64);
    if (lane < 32) { red[0][m][lane] = acc0; red[1][m][lane] = acc1; }
    __syncthreads();
    if (tid < 64) {
        int qq = tid >> 5, ee = tid & 31;
        out[(size_t)i0*32 + tid] =
            red[qq][0][ee] + red[qq][1][ee] + red[qq][2][ee] + red[qq][3][ee];
    }
}

extern "C" void kernel_launch(void* const* d_in, const int* in_sizes, int n_in,
                              void* d_out, int out_size, void* d_ws, size_t ws_size,
                              hipStream_t stream) {
    const float* x0   = (const float*)d_in[0];
    const float* x1   = (const float*)d_in[1];
    const float* x2   = (const float*)d_in[2];
    const float* x3   = (const float*)d_in[3];
    const float* wq_w = (const float*)d_in[4];
    const float* wq_b = (const float*)d_in[5];
    const float* wk_w = (const float*)d_in[6];
    const float* wk_b = (const float*)d_in[7];
    float* ws  = (float*)d_ws;
    float* out = (float*)d_out;

    hipLaunchKernelGGL(k_fused,  dim3(208),  dim3(256), 0, stream,
                       x0, x1, x2, x3, wq_w, wq_b, wk_w, wk_b, ws);
    hipLaunchKernelGGL(k_prefix, dim3(128),  dim3(64),  0, stream, ws);
    hipLaunchKernelGGL(k_query,  dim3(2048), dim3(256), 0, stream,
                       x0, x1, x2, x3, ws, out);
}

// Round 4
// 148.722 us; speedup vs baseline: 1.0417x; 1.0417x over previous
//
#include <hip/hip_runtime.h>

// Problem constants
//   m1:(1,1,4096,64) m2:(1,1,6144,64) m3:(1,1,8192,64) m4:(1,1,4096,64) fp32
//   WQ_w:(3,64,64) WQ_b:(3,64) WK_w:(4,3,64,64) WK_b:(4,3,64)
//   out:(1,4096,32) fp32
//
// Workspace layout (floats):
//   Q    row-major [4096][64]            @ 0          (262144)
//   K_T  per module [64][T_m]            @ 262144     (1441792)
//   SP   356 slots x 2048 (d*32+e)       @ 1703936    (729088)
//   TD   dense t2 per module             @ 2433024    (22528)
//   CTAB int[4][64][2] tile c-bounds     @ 2455552    (512)

#define QT_OFF   0
#define KT_OFF   262144
#define SP_OFF   1703936
#define TD_OFF   2433024
#define C_OFF    2455552

// ---------------------------------------------------------------------------
// Fused MLP + per-tile chunk outer-product sums (unchanged from R3 — verified).
__global__ __launch_bounds__(256) void k_fused(
    const float* __restrict__ x0, const float* __restrict__ x1,
    const float* __restrict__ x2, const float* __restrict__ x3,
    const float* __restrict__ wq_w, const float* __restrict__ wq_b,
    const float* __restrict__ wk_w, const float* __restrict__ wk_b,
    float* __restrict__ ws)
{
    __shared__ float sW[64*64];    // W layer; reused as V tile [128][32]
    __shared__ float sH[64*130];   // h[d][r]; reused as K[d][r]
    __shared__ float so[64*33];    // chunk-output transpose staging

    const int tid = threadIdx.x;
    const int bid = blockIdx.x;

    int task, rb;
    if (bid < 32)       { task = 0; rb = bid; }
    else if (bid < 64)  { task = 1; rb = bid - 32; }
    else if (bid < 112) { task = 2; rb = bid - 64; }
    else if (bid < 176) { task = 3; rb = bid - 112; }
    else                { task = 4; rb = bid - 176; }

    const float* Xs[4] = {x0, x1, x2, x3};
    const int Tm[4]     = {4096, 6144, 8192, 4096};
    const int rowoff[4] = {0, 4096, 10240, 18432};
    const int spoff[4]  = {0, 65, 162, 291};

    const float* X; const float* W; const float* Bv;
    int mm = -1;
    if (task == 0) { X = x0; W = wq_w; Bv = wq_b; }
    else {
        mm = task - 1;
        X = Xs[mm]; W = wk_w + mm*3*64*64; Bv = wk_b + mm*3*64;
    }

    const int row0 = rb * 128;
    const float4* X4 = (const float4*)(X + (size_t)row0*64);
    #pragma unroll
    for (int k = 0; k < 8; ++k) {
        int idx = k*256 + tid;
        float4 v = X4[idx];
        int db = idx * 4;
        int d0 = db & 63;
        int rr = db >> 6;
        sH[(d0+0)*130 + rr] = v.x;
        sH[(d0+1)*130 + rr] = v.y;
        sH[(d0+2)*130 + rr] = v.z;
        sH[(d0+3)*130 + rr] = v.w;
    }
    __syncthreads();
    if (task > 0 && tid < 128)
        ws[TD_OFF + rowoff[mm] + row0 + tid] = sH[63*130 + tid];

    const int r  = tid & 63;
    const int cb = (tid >> 6) * 16;

    float a0[16], a1[16];
    #pragma unroll 1
    for (int l = 0; l < 3; ++l) {
        __syncthreads();
        const float4* W4 = (const float4*)(W + l*4096);
        #pragma unroll
        for (int k = 0; k < 4; ++k)
            ((float4*)sW)[k*256 + tid] = W4[k*256 + tid];
        __syncthreads();

        #pragma unroll
        for (int c = 0; c < 16; ++c) {
            float b = Bv[l*64 + cb + c];
            a0[c] = b; a1[c] = b;
        }
        for (int d = 0; d < 64; ++d) {
            float h0 = sH[d*130 + r];
            float h1 = sH[d*130 + 64 + r];
            #pragma unroll
            for (int c = 0; c < 16; ++c) {
                float w = sW[d*64 + cb + c];
                a0[c] += h0 * w;
                a1[c] += h1 * w;
            }
        }
        if (l < 2) {
            #pragma unroll
            for (int c = 0; c < 16; ++c) {
                a0[c] = fmaxf(a0[c], 0.0f);
                a1[c] = fmaxf(a1[c], 0.0f);
            }
            __syncthreads();
            #pragma unroll
            for (int c = 0; c < 16; ++c) {
                sH[(cb+c)*130 + r]      = a0[c];
                sH[(cb+c)*130 + 64 + r] = a1[c];
            }
        }
    }

    if (task == 0) {
        float* q0 = ws + QT_OFF + (size_t)(row0 + r)*64 + cb;
        float* q1 = ws + QT_OFF + (size_t)(row0 + 64 + r)*64 + cb;
        #pragma unroll
        for (int k = 0; k < 4; ++k) {
            ((float4*)q0)[k] = make_float4(a0[4*k], a0[4*k+1], a0[4*k+2], a0[4*k+3]);
            ((float4*)q1)[k] = make_float4(a1[4*k], a1[4*k+1], a1[4*k+2], a1[4*k+3]);
        }
        return;
    }

    {
        float* outT = ws + KT_OFF + (size_t)64*rowoff[mm];
        const int stride = Tm[mm];
        #pragma unroll
        for (int c = 0; c < 16; ++c) {
            outT[(size_t)(cb+c)*stride + row0 + r]      = a0[c];
            outT[(size_t)(cb+c)*stride + row0 + 64 + r] = a1[c];
        }
    }
    __syncthreads();
    #pragma unroll
    for (int c = 0; c < 16; ++c) {
        sH[(cb+c)*130 + r]      = a0[c];
        sH[(cb+c)*130 + 64 + r] = a1[c];
    }
    {
        const float4* Xr = (const float4*)(X + (size_t)row0*64);
        #pragma unroll
        for (int k = 0; k < 4; ++k) {
            int idx = k*256 + tid;
            int rr = idx >> 3, c4 = idx & 7;
            ((float4*)sW)[rr*8 + c4] = Xr[rr*16 + c4];
        }
    }
    float* spbase = ws + SP_OFF + (size_t)spoff[mm]*2048;
    if (rb == 0)
        for (int idx = tid; idx < 2048; idx += 256) spbase[idx] = 0.0f;
    __syncthreads();

    const int d  = tid & 63;
    const int eg = tid >> 6;
    const float4* vb4 = (const float4*)sW;
    #pragma unroll 1
    for (int pass = 0; pass < 2; ++pass) {
        float acc[8] = {0,0,0,0,0,0,0,0};
        for (int j = 0; j < 64; ++j) {
            int rr = pass*64 + j;
            float  kd = sH[d*130 + rr];
            float4 vA = vb4[rr*8 + eg*2 + 0];
            float4 vB = vb4[rr*8 + eg*2 + 1];
            acc[0] += kd * vA.x; acc[1] += kd * vA.y;
            acc[2] += kd * vA.z; acc[3] += kd * vA.w;
            acc[4] += kd * vB.x; acc[5] += kd * vB.y;
            acc[6] += kd * vB.z; acc[7] += kd * vB.w;
        }
        #pragma unroll
        for (int u = 0; u < 8; ++u)
            so[d*33 + eg*8 + u] = acc[u];
        __syncthreads();
        float* slot = spbase + (size_t)(2*rb + pass + 1) * 2048;
        for (int idx = tid; idx < 2048; idx += 256)
            slot[idx] = so[(idx >> 5)*33 + (idx & 31)];
        __syncthreads();
    }
}

// ---------------------------------------------------------------------------
// Blocks 0..127: in-place scan over SP slots (one thread per entry-chain).
// Blocks 128..129: compute per-tile c-bounds table (2 searches per tile) —
// removes ALL searches from k_query.
__global__ __launch_bounds__(64) void k_prefix(float* __restrict__ ws)
{
    const int nslots[4] = {65, 97, 129, 65};
    const int spoff[4]  = {0, 65, 162, 291};
    const int Tm[4]     = {4096, 6144, 8192, 4096};
    const int rowoff[4] = {0, 4096, 10240, 18432};
    const int bid = blockIdx.x;

    if (bid < 128) {
        const int m = bid >> 5;
        const int entry = (bid & 31)*64 + threadIdx.x;
        float* p = ws + SP_OFF + (size_t)spoff[m]*2048 + entry;
        const int n = nslots[m];
        float s = 0.0f;
        #pragma unroll 8
        for (int k = 0; k < n; ++k) {
            float v = p[(size_t)k*2048];
            s += v;
            p[(size_t)k*2048] = s;
        }
        return;
    }
    // tile bounds: g = m*128 + tile*2 + bound
    const float* td = ws + TD_OFF;
    int* ctab = (int*)(ws + C_OFF);
    #pragma unroll 1
    for (int k = 0; k < 4; ++k) {
        int g = (bid - 128)*256 + k*64 + threadIdx.x;   // 0..511
        int m = g >> 7;
        int tile = (g >> 1) & 63;
        int bound = g & 1;
        float t = td[tile*64 + (bound ? 63 : 0)];       // t1 endpoints
        const float* t2 = td + rowoff[m];
        int lo = 0, hi = Tm[m];
        while (lo < hi) {
            int mid = (lo + hi) >> 1;
            if (t2[mid] <= t) lo = mid + 1; else hi = mid;
        }
        ctab[g] = lo;
    }
}

// ---------------------------------------------------------------------------
// Tiled query kernel: block = (module m, tile of 64 consecutive queries).
// out_i = Q_i S_{B0} + sum over boundary chunks of mask(t2_j<=t1_i)*(Q_i.K_j) V_j.
// Dense LDS GEMMs, no searches, no shuffles. fp32 atomicAdd across modules.
__global__ __launch_bounds__(256) void k_query(
    const float* __restrict__ x0, const float* __restrict__ x1,
    const float* __restrict__ x2, const float* __restrict__ x3,
    const float* __restrict__ ws, float* __restrict__ out)
{
    __shared__ float qs[64*65];    // Q[i][d], pad 65 (2-way free)
    __shared__ float kc[64*64];    // K[d][j], broadcast-read only
    __shared__ float vc[64*36];    // V[j][e], pad 36 (aligned, cf writes)
    __shared__ float ss[64*32];    // state slot S[d][e]
    __shared__ float ps[64*67];    // masked P[i][j], pad 67 (2-way free)
    __shared__ float tq[64];       // t1 tile
    __shared__ float tcs[64];      // t2 chunk

    const int tid  = threadIdx.x;
    const int m    = blockIdx.x & 3;
    const int tile = blockIdx.x >> 2;
    const int i0   = tile * 64;

    const float* Xs[4] = {x0, x1, x2, x3};
    const int Tm[4]     = {4096, 6144, 8192, 4096};
    const int rowoff[4] = {0, 4096, 10240, 18432};
    const int spoff[4]  = {0, 65, 162, 291};
    const int T = Tm[m];
    (void)Xs;

    const int* ctab = (const int*)(ws + C_OFF);
    const int c_lo = ctab[m*128 + tile*2 + 0];
    const int c_hi = ctab[m*128 + tile*2 + 1];
    const int B0   = c_lo >> 6;
    const int Bhi  = (c_hi + 63) >> 6;

    const float* Q  = ws + QT_OFF;
    const float* Kt = ws + KT_OFF + (size_t)64*rowoff[m];
    const float* td = ws + TD_OFF;
    const float* sp = ws + SP_OFF + (size_t)(spoff[m] + B0)*2048;

    // ---- stage Q tile, state slot, t1 tile ----
    {
        const float4* Q4 = (const float4*)(Q + (size_t)i0*64);
        #pragma unroll
        for (int k = 0; k < 4; ++k) {
            int idx = k*256 + tid;          // float4 idx in 64x64
            float4 v = Q4[idx];
            int i = idx >> 4, d4 = (idx & 15)*4;
            qs[i*65 + d4 + 0] = v.x;
            qs[i*65 + d4 + 1] = v.y;
            qs[i*65 + d4 + 2] = v.z;
            qs[i*65 + d4 + 3] = v.w;
        }
        const float4* S4 = (const float4*)sp;
        #pragma unroll
        for (int k = 0; k < 2; ++k)
            ((float4*)ss)[k*256 + tid] = S4[k*256 + tid];
        if (tid < 64) tq[tid] = td[i0 + tid];
    }
    __syncthreads();

    const int il = tid & 63;        // query row within tile (lane)
    const int eg = tid >> 6;        // wave id: e-group (state/PV) and j-quarter (S)
    float acc[8] = {0,0,0,0,0,0,0,0};

    // ---- state part: acc[e] += sum_d Q[i][d] * S[d][e] ----
    for (int d = 0; d < 64; ++d) {
        float q = qs[il*65 + d];                        // 2-way, free
        const float4* s4 = (const float4*)&ss[d*32 + eg*8];  // broadcast
        float4 sA = s4[0], sB = s4[1];
        acc[0] += q * sA.x; acc[1] += q * sA.y;
        acc[2] += q * sA.z; acc[3] += q * sA.w;
        acc[4] += q * sB.x; acc[5] += q * sB.y;
        acc[6] += q * sB.z; acc[7] += q * sB.w;
    }

    // ---- boundary chunks with explicit time mask ----
    #pragma unroll 1
    for (int B = B0; B < Bhi; ++B) {
        __syncthreads();   // prior pass2 reads of vc/ps complete
        // load K chunk: kc[d][j] = Kt[d*T + B*64 + j]
        #pragma unroll
        for (int k = 0; k < 4; ++k) {
            int idx = k*256 + tid;
            int d = idx >> 4, j4 = (idx & 15)*4;
            float4 v = *(const float4*)&Kt[(size_t)d*T + B*64 + j4];
            *(float4*)&kc[d*64 + j4] = v;
        }
        // load V chunk: vc[j][e] = X[(B*64+j)*64 + e], e<32
        {
            const float* Xm = Xs[m];
            #pragma unroll
            for (int k = 0; k < 2; ++k) {
                int idx = k*256 + tid;
                int j = idx >> 3, e4 = (idx & 7)*4;
                float4 v = *(const float4*)&Xm[(size_t)(B*64 + j)*64 + e4];
                *(float4*)&vc[j*36 + e4] = v;
            }
        }
        if (tid < 64) tcs[tid] = td[rowoff[m] + B*64 + tid];
        __syncthreads();

        // pass 1: s[c] = Q_i . K_{jq*16+c};  mask; write ps[i][j]
        {
            float s[16];
            #pragma unroll
            for (int c = 0; c < 16; ++c) s[c] = 0.0f;
            for (int d = 0; d < 64; ++d) {
                float q = qs[il*65 + d];
                const float4* kr = (const float4*)&kc[d*64 + eg*16]; // broadcast
                float4 k0 = kr[0], k1 = kr[1], k2 = kr[2], k3 = kr[3];
                s[0]  += q * k0.x; s[1]  += q * k0.y; s[2]  += q * k0.z; s[3]  += q * k0.w;
                s[4]  += q * k1.x; s[5]  += q * k1.y; s[6]  += q * k1.z; s[7]  += q * k1.w;
                s[8]  += q * k2.x; s[9]  += q * k2.y; s[10] += q * k2.z; s[11] += q * k2.w;
                s[12] += q * k3.x; s[13] += q * k3.y; s[14] += q * k3.z; s[15] += q * k3.w;
            }
            float myt = tq[il];
            #pragma unroll
            for (int c = 0; c < 16; ++c) {
                float p = (tcs[eg*16 + c] <= myt) ? s[c] : 0.0f;
                ps[il*67 + eg*16 + c] = p;       // bank 3*il+j: 2-way, free
            }
        }
        __syncthreads();

        // pass 2: acc[e] += sum_j ps[i][j] * V[j][e]
        for (int j = 0; j < 64; ++j) {
            float p = ps[il*67 + j];                     // 2-way, free
            const float4* v4 = (const float4*)&vc[j*36 + eg*8];  // broadcast
            float4 vA = v4[0], vB = v4[1];
            acc[0] += p * vA.x; acc[1] += p * vA.y;
            acc[2] += p * vA.z; acc[3] += p * vA.w;
            acc[4] += p * vB.x; acc[5] += p * vB.y;
            acc[6] += p * vB.z; acc[7] += p * vB.w;
        }
    }

    // ---- combine modules via fp32 atomics (d_out pre-zeroed) ----
    float* op = out + (size_t)(i0 + il)*32 + eg*8;
    #pragma unroll
    for (int u = 0; u < 8; ++u)
        atomicAdd(&op[u], acc[u]);
}

extern "C" void kernel_launch(void* const* d_in, const int* in_sizes, int n_in,
                              void* d_out, int out_size, void* d_ws, size_t ws_size,
                              hipStream_t stream) {
    const float* x0   = (const float*)d_in[0];
    const float* x1   = (const float*)d_in[1];
    const float* x2   = (const float*)d_in[2];
    const float* x3   = (const float*)d_in[3];
    const float* wq_w = (const float*)d_in[4];
    const float* wq_b = (const float*)d_in[5];
    const float* wk_w = (const float*)d_in[6];
    const float* wk_b = (const float*)d_in[7];
    float* ws  = (float*)d_ws;
    float* out = (float*)d_out;

    hipMemsetAsync(out, 0, (size_t)out_size * sizeof(float), stream);
    hipLaunchKernelGGL(k_fused,  dim3(208), dim3(256), 0, stream,
                       x0, x1, x2, x3, wq_w, wq_b, wk_w, wk_b, ws);
    hipLaunchKernelGGL(k_prefix, dim3(130), dim3(64),  0, stream, ws);
    hipLaunchKernelGGL(k_query,  dim3(256), dim3(256), 0, stream,
                       x0, x1, x2, x3, ws, out);
}

// Round 5
// 115.595 us; speedup vs baseline: 1.3402x; 1.2866x over previous
//
#include <hip/hip_runtime.h>

// Problem constants
//   m1:(1,1,4096,64) m2:(1,1,6144,64) m3:(1,1,8192,64) m4:(1,1,4096,64) fp32
//   WQ_w:(3,64,64) WQ_b:(3,64) WK_w:(4,3,64,64) WK_b:(4,3,64)
//   out:(1,4096,32) fp32
//
// Workspace layout (float units):
//   Qb   bf16 [4096][64]                 @ 0          (131072 fl)
//   Kb   bf16 per module [T_m][64]       @ 131072     (720896 fl)
//   SP   fp32 356 slots x 2048 (d*32+e)  @ 851968     (729088 fl)
//   TD   fp32 dense t2 per module        @ 1581056    (22528 fl)
//   CTAB int[4][64][2] tile c-bounds     @ 1603584    (512)

#define QB_OFF   0
#define KB_OFF   131072
#define SP_OFF   851968
#define TD_OFF   1581056
#define C_OFF    1603584

typedef __attribute__((ext_vector_type(8))) short short8;    // bf16 frag (4 VGPR)
typedef __attribute__((ext_vector_type(4))) float floatx4;   // MFMA C/D

__device__ __forceinline__ unsigned short f2bf(float f) {
    union { float f; unsigned u; } v; v.f = f;
    unsigned r = v.u + 0x7fff + ((v.u >> 16) & 1);   // RNE
    return (unsigned short)(r >> 16);
}

#define MFMA16(a,b,c) __builtin_amdgcn_mfma_f32_16x16x32_bf16((a),(b),(c),0,0,0)

// ---------------------------------------------------------------------------
// Fused: 3-layer MLP (bf16 MFMA) + bf16 Q/K global store + chunk K^T·V sums.
// 128-row tiles. Tiles: Q:32 | K m0:32 | m1:48 | m2:64 | m3:32 -> 208 blocks.
__global__ __launch_bounds__(256) void k_fused(
    const float* __restrict__ x0, const float* __restrict__ x1,
    const float* __restrict__ x2, const float* __restrict__ x3,
    const float* __restrict__ wq_w, const float* __restrict__ wq_b,
    const float* __restrict__ wk_w, const float* __restrict__ wk_b,
    float* __restrict__ ws)
{
    __shared__ unsigned short H0[128*72];   // act buffer A  [row][d]
    __shared__ unsigned short H1[128*72];   // act buffer B  [row][d]
    __shared__ unsigned short Wt[64*72];    // W^T layer     [c][d]
    __shared__ unsigned short KT[64*136];   // K^T           [d][j]  j=0..127
    __shared__ unsigned short VT[32*136];   // V^T           [e][j]  j=0..127

    const int tid = threadIdx.x;
    const int bid = blockIdx.x;

    int task, rb;
    if (bid < 32)       { task = 0; rb = bid; }
    else if (bid < 64)  { task = 1; rb = bid - 32; }
    else if (bid < 112) { task = 2; rb = bid - 64; }
    else if (bid < 176) { task = 3; rb = bid - 112; }
    else                { task = 4; rb = bid - 176; }

    const float* Xs[4] = {x0, x1, x2, x3};
    const int rowoff[4] = {0, 4096, 10240, 18432};
    const int spoff[4]  = {0, 65, 162, 291};

    const float* X; const float* W; const float* Bv;
    int mm = -1;
    if (task == 0) { X = x0; W = wq_w; Bv = wq_b; }
    else {
        mm = task - 1;
        X = Xs[mm]; W = wk_w + mm*3*64*64; Bv = wk_b + mm*3*64;
    }

    const int row0 = rb * 128;

    // stage X tile -> H0 (bf16 [row][d])
    {
        const float4* X4 = (const float4*)(X + (size_t)row0*64);
        #pragma unroll
        for (int k = 0; k < 8; ++k) {
            int idx = k*256 + tid;            // 0..2047 float4s
            float4 v = X4[idx];
            int rr = idx >> 4, c4 = (idx & 15) * 4;
            ushort4 h;
            h.x = f2bf(v.x); h.y = f2bf(v.y); h.z = f2bf(v.z); h.w = f2bf(v.w);
            *(ushort4*)&H0[rr*72 + c4] = h;
        }
    }
    // dense timestamps straight from global fp32 (must NOT go through bf16)
    if (task > 0 && tid < 128)
        ws[TD_OFF + rowoff[mm] + row0 + tid] = X[(size_t)(row0 + tid)*64 + 63];

    const int w    = tid >> 6;      // wave id = n-tile
    const int lane = tid & 63;
    const int lm   = lane & 15;
    const int q    = lane >> 4;

    #pragma unroll 1
    for (int l = 0; l < 3; ++l) {
        __syncthreads();            // prior-layer frag reads / X stage done
        // stage W^T for this layer
        {
            const float4* W4 = (const float4*)(W + l*4096);
            #pragma unroll
            for (int k = 0; k < 4; ++k) {
                int idx = k*256 + tid;        // 0..1023
                float4 v = W4[idx];
                int d = idx >> 4, c4 = (idx & 15) * 4;
                Wt[(c4+0)*72 + d] = f2bf(v.x);
                Wt[(c4+1)*72 + d] = f2bf(v.y);
                Wt[(c4+2)*72 + d] = f2bf(v.z);
                Wt[(c4+3)*72 + d] = f2bf(v.w);
            }
        }
        __syncthreads();

        const unsigned short* Hin  = (l & 1) ? H1 : H0;
        unsigned short*       Hout = (l & 1) ? H0 : H1;
        float bias = Bv[l*64 + w*16 + lm];
        short8 b0 = *(const short8*)&Wt[(w*16+lm)*72 + q*8];
        short8 b1 = *(const short8*)&Wt[(w*16+lm)*72 + 32 + q*8];
        #pragma unroll
        for (int mt = 0; mt < 8; ++mt) {
            floatx4 acc = {bias, bias, bias, bias};
            short8 a0 = *(const short8*)&Hin[(mt*16+lm)*72 + q*8];
            short8 a1 = *(const short8*)&Hin[(mt*16+lm)*72 + 32 + q*8];
            acc = MFMA16(a0, b0, acc);
            acc = MFMA16(a1, b1, acc);
            int r0 = mt*16 + q*4;
            #pragma unroll
            for (int r = 0; r < 4; ++r) {
                float f = acc[r];
                if (l < 2) f = fmaxf(f, 0.0f);
                unsigned short hb = f2bf(f);
                Hout[(r0+r)*72 + w*16 + lm] = hb;            // [row][col]
                if (l == 2 && task > 0)
                    KT[(w*16+lm)*136 + r0 + r] = hb;         // K^T [d][j]
            }
        }
    }
    __syncthreads();

    // coalesced global bf16 store of the final activations (Q or K)
    {
        unsigned short* dst = (task == 0)
            ? (unsigned short*)(ws + QB_OFF)
            : (unsigned short*)(ws + KB_OFF) + (size_t)rowoff[mm]*64;
        #pragma unroll
        for (int k = 0; k < 8; ++k) {
            int idx = k*256 + tid;            // 0..2047 ushort4s
            int rr = idx >> 4, c4 = (idx & 15) * 4;
            *(ushort4*)&dst[(size_t)(row0 + rr)*64 + c4] = *(ushort4*)&H1[rr*72 + c4];
        }
    }
    if (task == 0) return;

    // stage V^T (X cols 0..31, bf16) + zero module slot 0
    {
        #pragma unroll
        for (int k = 0; k < 4; ++k) {
            int idx = k*256 + tid;            // 0..1023 float4s
            int j = idx >> 3, e4 = (idx & 7) * 4;
            float4 v = *(const float4*)&X[(size_t)(row0 + j)*64 + e4];
            VT[(e4+0)*136 + j] = f2bf(v.x);
            VT[(e4+1)*136 + j] = f2bf(v.y);
            VT[(e4+2)*136 + j] = f2bf(v.z);
            VT[(e4+3)*136 + j] = f2bf(v.w);
        }
    }
    float* spbase = ws + SP_OFF + (size_t)spoff[mm]*2048;
    if (rb == 0)
        for (int idx = tid; idx < 2048; idx += 256) spbase[idx] = 0.0f;
    __syncthreads();

    // chunk sums S_c[d][e] = sum_j K[j][d] V[j][e]  via MFMA (A=K^T, B=V)
    // wave w -> d-tile w; nt in {0,1} covers e=0..31; 2 chunks of 64 rows
    #pragma unroll 1
    for (int c = 0; c < 2; ++c) {
        float* slot = spbase + (size_t)(2*rb + c + 1) * 2048;
        #pragma unroll
        for (int nt = 0; nt < 2; ++nt) {
            floatx4 acc = {0.f, 0.f, 0.f, 0.f};
            #pragma unroll
            for (int ks = 0; ks < 2; ++ks) {
                short8 a = *(const short8*)&KT[(w*16+lm)*136 + c*64 + ks*32 + q*8];
                short8 b = *(const short8*)&VT[(nt*16+lm)*136 + c*64 + ks*32 + q*8];
                acc = MFMA16(a, b, acc);
            }
            #pragma unroll
            for (int r = 0; r < 4; ++r) {
                int d = w*16 + q*4 + r;
                int e = nt*16 + lm;
                slot[d*32 + e] = acc[r];
            }
        }
    }
}

// ---------------------------------------------------------------------------
// Blocks 0..127: in-place fp32 scan over SP slots. Blocks 128..129: tile
// c-bounds table (2 binary searches per tile).
__global__ __launch_bounds__(64) void k_prefix(float* __restrict__ ws)
{
    const int nslots[4] = {65, 97, 129, 65};
    const int spoff[4]  = {0, 65, 162, 291};
    const int Tm[4]     = {4096, 6144, 8192, 4096};
    const int rowoff[4] = {0, 4096, 10240, 18432};
    const int bid = blockIdx.x;

    if (bid < 128) {
        const int m = bid >> 5;
        const int entry = (bid & 31)*64 + threadIdx.x;
        float* p = ws + SP_OFF + (size_t)spoff[m]*2048 + entry;
        const int n = nslots[m];
        float s = 0.0f;
        #pragma unroll 8
        for (int k = 0; k < n; ++k) {
            float v = p[(size_t)k*2048];
            s += v;
            p[(size_t)k*2048] = s;
        }
        return;
    }
    const float* td = ws + TD_OFF;
    int* ctab = (int*)(ws + C_OFF);
    #pragma unroll 1
    for (int k = 0; k < 4; ++k) {
        int g = (bid - 128)*256 + k*64 + threadIdx.x;   // 0..511
        int m = g >> 7;
        int tile = (g >> 1) & 63;
        int bound = g & 1;
        float t = td[tile*64 + (bound ? 63 : 0)];
        const float* t2 = td + rowoff[m];
        int lo = 0, hi = Tm[m];
        while (lo < hi) {
            int mid = (lo + hi) >> 1;
            if (t2[mid] <= t) lo = mid + 1; else hi = mid;
        }
        ctab[g] = lo;
    }
}

// ---------------------------------------------------------------------------
// Tiled MFMA query kernel: block = (module m, 64-query tile). 256 blocks.
// O = Q·S_B0 + sum over boundary chunks of mask(QK^T)·V,  all bf16 MFMA.
__global__ __launch_bounds__(256) void k_query(
    const float* __restrict__ x0, const float* __restrict__ x1,
    const float* __restrict__ x2, const float* __restrict__ x3,
    float* __restrict__ ws, float* __restrict__ out)
{
    __shared__ unsigned short qs[64*72];   // Q  [i][d]
    __shared__ unsigned short kc[64*72];   // K  [j][d]  (chunk)
    __shared__ unsigned short vt[32*72];   // V^T [e][j] (chunk)
    __shared__ unsigned short st[32*72];   // S^T [e][d]
    __shared__ unsigned short ps[64*72];   // masked P [i][j] (chunk)
    __shared__ float tq[64];               // t1 tile (fp32!)
    __shared__ float tcs[64];              // t2 chunk (fp32!)

    const int tid  = threadIdx.x;
    const int m    = blockIdx.x & 3;
    const int tile = blockIdx.x >> 2;
    const int i0   = tile * 64;

    const float* Xs[4] = {x0, x1, x2, x3};
    const int rowoff[4] = {0, 4096, 10240, 18432};
    const int spoff[4]  = {0, 65, 162, 291};
    const float* X = Xs[m];

    const int* ctab = (const int*)(ws + C_OFF);
    const int c_lo = ctab[m*128 + tile*2 + 0];
    const int c_hi = ctab[m*128 + tile*2 + 1];
    const int B0   = c_lo >> 6;
    const int Bhi  = (c_hi + 63) >> 6;

    const unsigned short* Qg = (const unsigned short*)(ws + QB_OFF);
    const unsigned short* Kg = (const unsigned short*)(ws + KB_OFF) + (size_t)rowoff[m]*64;
    const float* td = ws + TD_OFF;
    const float* sp = ws + SP_OFF + (size_t)(spoff[m] + B0)*2048;

    // ---- stage Q (bf16 copy), S^T (fp32->bf16), t1 ----
    {
        #pragma unroll
        for (int k = 0; k < 4; ++k) {
            int idx = k*256 + tid;            // 0..1023 ushort4s
            int rr = idx >> 4, c4 = (idx & 15) * 4;
            *(ushort4*)&qs[rr*72 + c4] = *(const ushort4*)&Qg[(size_t)(i0 + rr)*64 + c4];
        }
        #pragma unroll
        for (int k = 0; k < 8; ++k) {
            int idx = k*256 + tid;            // 0..2047
            int d = idx >> 5, e = idx & 31;
            st[e*72 + d] = f2bf(sp[idx]);
        }
        if (tid < 64) tq[tid] = td[i0 + tid];
    }
    __syncthreads();

    const int w    = tid >> 6;
    const int lane = tid & 63;
    const int lm   = lane & 15;
    const int q    = lane >> 4;

    // per-lane t1 values for masking (C-layout rows)
    float t1v[16];
    #pragma unroll
    for (int mt = 0; mt < 4; ++mt)
        #pragma unroll
        for (int r = 0; r < 4; ++r)
            t1v[mt*4 + r] = tq[mt*16 + q*4 + r];

    // resident Q A-frags: qa[mt][ks]
    short8 qa[4][2];
    #pragma unroll
    for (int mt = 0; mt < 4; ++mt) {
        qa[mt][0] = *(const short8*)&qs[(mt*16+lm)*72 + q*8];
        qa[mt][1] = *(const short8*)&qs[(mt*16+lm)*72 + 32 + q*8];
    }

    // ---- state part: O = Q · S   (wave w owns m-tile w) ----
    floatx4 accO[2];
    #pragma unroll
    for (int nt = 0; nt < 2; ++nt) {
        floatx4 acc = {0.f, 0.f, 0.f, 0.f};
        #pragma unroll
        for (int ks = 0; ks < 2; ++ks) {
            short8 b = *(const short8*)&st[(nt*16+lm)*72 + ks*32 + q*8];
            acc = MFMA16(qa[w][ks], b, acc);
        }
        accO[nt] = acc;
    }

    // ---- boundary chunks ----
    #pragma unroll 1
    for (int B = B0; B < Bhi; ++B) {
        __syncthreads();   // prior chunk's kc/vt/ps/tcs reads complete
        #pragma unroll
        for (int k = 0; k < 4; ++k) {
            int idx = k*256 + tid;            // K chunk: 1024 ushort4s
            int j = idx >> 4, c4 = (idx & 15) * 4;
            *(ushort4*)&kc[j*72 + c4] = *(const ushort4*)&Kg[(size_t)(B*64 + j)*64 + c4];
        }
        #pragma unroll
        for (int k = 0; k < 2; ++k) {
            int idx = k*256 + tid;            // V chunk: 512 float4s
            int j = idx >> 3, e4 = (idx & 7) * 4;
            float4 v = *(const float4*)&X[(size_t)(B*64 + j)*64 + e4];
            vt[(e4+0)*72 + j] = f2bf(v.x);
            vt[(e4+1)*72 + j] = f2bf(v.y);
            vt[(e4+2)*72 + j] = f2bf(v.z);
            vt[(e4+3)*72 + j] = f2bf(v.w);
        }
        if (tid < 64) tcs[tid] = td[rowoff[m] + B*64 + tid];
        __syncthreads();

        // pass 1: scores S = Q·K^T for n-tile w; mask in fp32; write ps bf16
        {
            short8 bk0 = *(const short8*)&kc[(w*16+lm)*72 + q*8];
            short8 bk1 = *(const short8*)&kc[(w*16+lm)*72 + 32 + q*8];
            float t2j = tcs[w*16 + lm];
            #pragma unroll
            for (int mt = 0; mt < 4; ++mt) {
                floatx4 f = {0.f, 0.f, 0.f, 0.f};
                f = MFMA16(qa[mt][0], bk0, f);
                f = MFMA16(qa[mt][1], bk1, f);
                #pragma unroll
                for (int r = 0; r < 4; ++r) {
                    float p = (t2j <= t1v[mt*4 + r]) ? f[r] : 0.0f;
                    ps[(mt*16 + q*4 + r)*72 + w*16 + lm] = f2bf(p);
                }
            }
        }
        __syncthreads();

        // pass 2: O += P·V  (wave w owns m-tile w)
        {
            short8 pa0 = *(const short8*)&ps[(w*16+lm)*72 + q*8];
            short8 pa1 = *(const short8*)&ps[(w*16+lm)*72 + 32 + q*8];
            #pragma unroll
            for (int nt = 0; nt < 2; ++nt) {
                short8 bv0 = *(const short8*)&vt[(nt*16+lm)*72 + q*8];
                short8 bv1 = *(const short8*)&vt[(nt*16+lm)*72 + 32 + q*8];
                accO[nt] = MFMA16(pa0, bv0, accO[nt]);
                accO[nt] = MFMA16(pa1, bv1, accO[nt]);
            }
        }
    }

    // ---- epilogue: atomic combine across modules (d_out pre-zeroed) ----
    #pragma unroll
    for (int nt = 0; nt < 2; ++nt)
        #pragma unroll
        for (int r = 0; r < 4; ++r) {
            int i = w*16 + q*4 + r;
            int e = nt*16 + lm;
            atomicAdd(&out[(size_t)(i0 + i)*32 + e], accO[nt][r]);
        }
}

extern "C" void kernel_launch(void* const* d_in, const int* in_sizes, int n_in,
                              void* d_out, int out_size, void* d_ws, size_t ws_size,
                              hipStream_t stream) {
    const float* x0   = (const float*)d_in[0];
    const float* x1   = (const float*)d_in[1];
    const float* x2   = (const float*)d_in[2];
    const float* x3   = (const float*)d_in[3];
    const float* wq_w = (const float*)d_in[4];
    const float* wq_b = (const float*)d_in[5];
    const float* wk_w = (const float*)d_in[6];
    const float* wk_b = (const float*)d_in[7];
    float* ws  = (float*)d_ws;
    float* out = (float*)d_out;

    hipMemsetAsync(out, 0, (size_t)out_size * sizeof(float), stream);
    hipLaunchKernelGGL(k_fused,  dim3(208), dim3(256), 0, stream,
                       x0, x1, x2, x3, wq_w, wq_b, wk_w, wk_b, ws);
    hipLaunchKernelGGL(k_prefix, dim3(130), dim3(64),  0, stream, ws);
    hipLaunchKernelGGL(k_query,  dim3(256), dim3(256), 0, stream,
                       x0, x1, x2, x3, ws, out);
}